// Round 19
// baseline (170.644 us; speedup 1.0000x reference)
//
#include <hip/hip_runtime.h>
#include <hip/hip_bf16.h>
#include <stdint.h>

// Problem constants
#define B_  4
#define T_  2048
#define C_  1024
#define H_  16
#define D_  64
#define BT  (B_*T_)     // 8192
#define KDIM 1024

typedef __attribute__((ext_vector_type(8))) short bf16x8;
typedef __attribute__((ext_vector_type(4))) float f32x4;

__device__ __forceinline__ unsigned short f2bf(float f) {
  union { float f; unsigned u; } v; v.f = f;
  unsigned r = v.u + 0x7FFFu + ((v.u >> 16) & 1u);   // RNE
  return (unsigned short)(r >> 16);
}

__device__ __forceinline__ float exp2_fast(float x) {   // raw v_exp_f32 (2^x)
  float r;
  asm("v_exp_f32 %0, %1" : "=v"(r) : "v"(x));
  return r;
}

// async global->LDS, 16B per lane. dest must be wave-uniform base + lane*16 (linear).
__device__ __forceinline__ void gld_lds16(const void* g, void* l) {
  __builtin_amdgcn_global_load_lds(
      (__attribute__((address_space(1))) unsigned int*)(uintptr_t)g,
      (__attribute__((address_space(3))) unsigned int*)(unsigned)(uintptr_t)l,
      16, 0, 0);
}

// ---------------------------------------------------------------- prep kernels
__global__ __launch_bounds__(256) void k_convert(
    const float* __restrict__ x,  const float* __restrict__ wq,
    const float* __restrict__ wk, const float* __restrict__ wv,
    const float* __restrict__ wp,
    unsigned short* __restrict__ xb, unsigned short* __restrict__ wcat,
    unsigned short* __restrict__ wpb)
{
  const int NX = BT*C_/4;       // 2097152 float4s of x
  const int NW = C_*C_/4;       // 262144 per W
  const int TOT = NX + 4*NW;
  for (int i = blockIdx.x*blockDim.x + threadIdx.x; i < TOT; i += gridDim.x*blockDim.x) {
    const float4* src; unsigned short* dst; int idx;
    if (i < NX)                { src = (const float4*)x;  dst = xb;            idx = i; }
    else {
      int j = i - NX;
      if (j < NW)              { src = (const float4*)wq; dst = wcat;          idx = j; }
      else if (j < 2*NW)       { src = (const float4*)wk; dst = wcat + C_*C_;  idx = j - NW; }
      else if (j < 3*NW)       { src = (const float4*)wv; dst = wcat + 2*C_*C_;idx = j - 2*NW; }
      else                     { src = (const float4*)wp; dst = wpb;           idx = j - 3*NW; }
    }
    float4 v = src[idx];
    ushort4 o; o.x = f2bf(v.x); o.y = f2bf(v.y); o.z = f2bf(v.z); o.w = f2bf(v.w);
    *(ushort4*)(dst + (size_t)idx*4) = o;
  }
}

// RoPE tables [T][D] (coalesced epilogue loads).
__global__ __launch_bounds__(256) void k_rope_tab(
    const int* __restrict__ start_pos, float* __restrict__ cosT, float* __restrict__ sinT)
{
  int i = blockIdx.x*blockDim.x + threadIdx.x;   // [0, T_*64)
  if (i >= T_*D_) return;
  int t = i >> 6, j = i & 63;
  float inv = exp2f(-(float)(j & 31) * (13.287712379549449f / 32.0f));
  float ang = (float)(t + start_pos[0]) * inv;
  cosT[i] = cosf(ang);
  sinT[i] = sinf(ang);
}

// ---------------------------------------------------------------- 256x256 16-wave GEMM, 64x64 wave-tiles
// (unchanged from R17 passing kernel: VGPR 60 + 64 AGPR -> 4 waves/SIMD)
__global__ __launch_bounds__(1024, 4) void k_gemm256(
    const unsigned short* __restrict__ A, const unsigned short* __restrict__ Bw,
    unsigned short* __restrict__ qb, unsigned short* __restrict__ kb,
    unsigned short* __restrict__ vt,
    const float* __restrict__ cosT, const float* __restrict__ sinT)
{
  __shared__ __attribute__((aligned(16))) char smem[131072];
  const int tid = threadIdx.x, l = tid & 63, w = tid >> 6;   // w in 0..15
  const int g = l >> 4, c = l & 15;
  const int m0 = blockIdx.x * 256, n0 = blockIdx.y * 256;
  const int wr = w >> 2, wc = w & 3;
  const char* gA = (const char*)A;
  const char* gB = (const char*)Bw;

  // staging descriptors: 2 x 16B per thread per 32KB unit; inverse of layout
  int dstP[2]; size_t aoff[2], boff[2];
#pragma unroll
  for (int j = 0; j < 2; ++j) {
    int P = j*16384 + tid*16;
    int row = P >> 7;                        // 0..255
    int kc = ((P & 127) ^ ((row & 7) << 4)) >> 1;
    dstP[j] = P;
    aoff[j] = ((size_t)(m0 + row) * KDIM + kc) * 2;
    boff[j] = ((size_t)(n0 + row) * KDIM + kc) * 2;
  }

  // frag-read constants: row = wr*64 + mi*16 + c -> row&7 == c&7
  const int aB = (wr*64 + c) * 128;            // + par + mi*2048 + xt
  const int bB = 32768 + (wc*64 + c) * 128;    // + par + ni*2048 + xt
  const int xsw = (c & 7) << 4;

  f32x4 acc[4][4];
#pragma unroll
  for (int i = 0; i < 4; ++i)
#pragma unroll
    for (int j = 0; j < 4; ++j) acc[i][j] = (f32x4){0.f,0.f,0.f,0.f};

  // prologue: stage tile 0 into parity 0
#pragma unroll
  for (int j = 0; j < 2; ++j) {
    gld_lds16(gA + aoff[j], smem + dstP[j]);
    gld_lds16(gB + boff[j], smem + 32768 + dstP[j]);
  }

  for (int t = 0; t < 16; ++t) {
    const int par = (t & 1) << 16;
    const int nxt = par ^ 65536;

    __syncthreads();   // drains last tile's stages (full tile old) + orders LDS

    if (t + 1 < 16) {
      const size_t ko = (size_t)(t + 1) * 128;
#pragma unroll
      for (int j = 0; j < 2; ++j) {
        gld_lds16(gA + aoff[j] + ko, smem + nxt + dstP[j]);
        gld_lds16(gB + boff[j] + ko, smem + nxt + 32768 + dstP[j]);
      }
    }

#pragma unroll
    for (int kk = 0; kk < 2; ++kk) {
      const int xt = (kk*64 + g*16) ^ xsw;
      bf16x8 af[4], bk[4];
#pragma unroll
      for (int ni = 0; ni < 4; ++ni)
        bk[ni] = *(const bf16x8*)(smem + par + bB + ni*2048 + xt);
#pragma unroll
      for (int mi = 0; mi < 4; ++mi)
        af[mi] = *(const bf16x8*)(smem + par + aB + mi*2048 + xt);
      __builtin_amdgcn_s_setprio(1);
#pragma unroll
      for (int mi = 0; mi < 4; ++mi)
#pragma unroll
        for (int ni = 0; ni < 4; ++ni)
          acc[mi][ni] = __builtin_amdgcn_mfma_f32_16x16x32_bf16(af[mi], bk[ni], acc[mi][ni], 0, 0, 0);
      __builtin_amdgcn_s_setprio(0);
    }
  }

  // epilogue: fused RoPE; C layout: col = lane&15, row = g*4 + r
#pragma unroll
  for (int mi = 0; mi < 4; ++mi) {
#pragma unroll
    for (int ni = 0; ni < 4; ++ni) {
      const int mrow0 = m0 + wr*64 + mi*16 + g*4;
      const int ncol  = n0 + wc*64 + ni*16 + c;
      const int which = ncol >> 10;          // 0=q 1=k 2=v (fragment-uniform)
      const int d = ncol & 1023, h = d >> 6, dd = d & 63;
      const int b = mrow0 >> 11, t0 = mrow0 & 2047;
      if (which == 2) {
        ushort4 o;
        o.x = f2bf(acc[mi][ni][0]); o.y = f2bf(acc[mi][ni][1]);
        o.z = f2bf(acc[mi][ni][2]); o.w = f2bf(acc[mi][ni][3]);
        *(ushort4*)(vt + ((size_t)((b*H_ + h)*D_ + dd))*T_ + t0) = o;
      } else {
#pragma unroll
        for (int r = 0; r < 4; ++r) {
          float val = acc[mi][ni][r];
          float partner = __shfl_xor(val, 1);          // value at dd^1 (lane^1)
          float rot = (dd & 1) ? partner : -partner;   // interleaved rotate_half
          float cv = cosT[(t0 + r)*64 + dd], sv = sinT[(t0 + r)*64 + dd];
          float o = val*cv + rot*sv;
          size_t oidx = (((size_t)(b*H_ + h))*T_ + (t0 + r))*D_ + dd;
          // q pre-scale: 1/sqrt(64) * log2(e)  (softmax done in exp2 domain)
          if (which == 0) qb[oidx] = f2bf(o * 0.180336879f);
          else            kb[oidx] = f2bf(o);
        }
      }
    }
  }
}

// ---------------------------------------------------------------- output-projection GEMM, 128x128, 8 waves
// R17 low-register recipe: 512 thr = 8 waves (2M x 4N), wave tile 64x32 ->
// acc[4][2] = 32 AGPR; 4 waves/SIMD (launch_bounds(512,4)).
// LDS 64KB dbuf (FIX from R18: array was 32KB while layout needs 64KB):
// parity p at p*32768: [A 16KB | B 16KB]; unit = 128 rows x 64 kc,
// byte = row*128 + (kc*2 ^ ((row&7)<<4)). 2 blocks/CU, grid 512 = 2x256 exact.
// Same 1-barrier/tile schedule + proven swizzle.
__global__ __launch_bounds__(512, 4) void k_gemm1(
    const unsigned short* __restrict__ A, const unsigned short* __restrict__ Bw,
    float* __restrict__ outF)
{
  __shared__ __attribute__((aligned(16))) char smem[65536];
  const int tid = threadIdx.x, l = tid & 63, w = tid >> 6;   // w in 0..7
  const int g = l >> 4, c = l & 15;
  const int m0 = blockIdx.x * 128, n0 = blockIdx.y * 128;
  const int wr = w >> 2, wc = w & 3;
  const char* gA = (const char*)A;
  const char* gB = (const char*)Bw;

  int dstP[2]; size_t aoff[2], boff[2];
#pragma unroll
  for (int j = 0; j < 2; ++j) {
    int P = j*8192 + tid*16;                 // [0, 16384)
    int row = P >> 7;                        // 0..127
    int kc = ((P & 127) ^ ((row & 7) << 4)) >> 1;
    dstP[j] = P;
    aoff[j] = ((size_t)(m0 + row) * KDIM + kc) * 2;
    boff[j] = ((size_t)(n0 + row) * KDIM + kc) * 2;
  }

  const int aB = (wr*64 + c) * 128;            // + par + mi*2048 + xt   (4 mi)
  const int bB = 16384 + (wc*32 + c) * 128;    // + par + ni*2048 + xt   (2 ni)
  const int xsw = (c & 7) << 4;

  f32x4 acc[4][2];
#pragma unroll
  for (int i = 0; i < 4; ++i)
#pragma unroll
    for (int j = 0; j < 2; ++j) acc[i][j] = (f32x4){0.f,0.f,0.f,0.f};

  // prologue: stage tile 0 into parity 0
#pragma unroll
  for (int j = 0; j < 2; ++j) {
    gld_lds16(gA + aoff[j], smem + dstP[j]);
    gld_lds16(gB + boff[j], smem + 16384 + dstP[j]);
  }

  for (int t = 0; t < 16; ++t) {
    const int par = (t & 1) << 15;           // 0 or 32768
    const int nxt = par ^ 32768;

    __syncthreads();

    if (t + 1 < 16) {
      const size_t ko = (size_t)(t + 1) * 128;   // +64 bf16 along K
#pragma unroll
      for (int j = 0; j < 2; ++j) {
        gld_lds16(gA + aoff[j] + ko, smem + nxt + dstP[j]);
        gld_lds16(gB + boff[j] + ko, smem + nxt + 16384 + dstP[j]);
      }
    }

#pragma unroll
    for (int kk = 0; kk < 2; ++kk) {
      const int xt = (kk*64 + g*16) ^ xsw;
      bf16x8 af[4], bk[2];
#pragma unroll
      for (int ni = 0; ni < 2; ++ni)
        bk[ni] = *(const bf16x8*)(smem + par + bB + ni*2048 + xt);
#pragma unroll
      for (int mi = 0; mi < 4; ++mi)
        af[mi] = *(const bf16x8*)(smem + par + aB + mi*2048 + xt);
      __builtin_amdgcn_s_setprio(1);
#pragma unroll
      for (int mi = 0; mi < 4; ++mi)
#pragma unroll
        for (int ni = 0; ni < 2; ++ni)
          acc[mi][ni] = __builtin_amdgcn_mfma_f32_16x16x32_bf16(af[mi], bk[ni], acc[mi][ni], 0, 0, 0);
      __builtin_amdgcn_s_setprio(0);
    }
  }

  // epilogue: f32 store; C layout: col = lane&15, row = g*4 + r
#pragma unroll
  for (int mi = 0; mi < 4; ++mi) {
#pragma unroll
    for (int ni = 0; ni < 2; ++ni) {
      const int mrow0 = m0 + wr*64 + mi*16 + g*4;
      const int ncol  = n0 + wc*32 + ni*16 + c;
#pragma unroll
      for (int r = 0; r < 4; ++r)
        outF[(size_t)(mrow0 + r) * 1024 + ncol] = acc[mi][ni][r];
    }
  }
}

// ---------------------------------------------------------------- flash attention
// (unchanged from R14-R17 passing kernel: 8 waves x 16 q-rows, XCD grid, 3-deep KV)
__global__ __launch_bounds__(512) void k_attn(
    const unsigned short* __restrict__ qb, const unsigned short* __restrict__ kb,
    const unsigned short* __restrict__ vt, unsigned short* __restrict__ yb)
{
  __shared__ __attribute__((aligned(16))) char smem[65536]; // 3x(K8K+V8K) + P:16K
  const int tid = threadIdx.x, l = tid & 63, w = tid >> 6;  // w in 0..7
  const int g = l >> 4, c = l & 15;
  const int bh = blockIdx.x;                 // x = bh -> XCD locality
  const int pidx = blockIdx.y;               // pair index 0..7
  const size_t bhO = (size_t)bh * T_ * D_;
  const int pbase = 49152 + w*2048;          // per-wave 2 KB P region
  const int b = bh >> 4, h = bh & 15;

  bf16x8 vones;
#pragma unroll
  for (int i = 0; i < 8; ++i) vones[i] = (short)0x3F80;   // bf16 1.0

  const char* srcK; const char* srcV; int dstP2;
  {
    int P = w*1024 + l*16;                 // [0, 8192)
    int row = P >> 7;
    int Lb = P ^ ((row & 7) << 4);
    int col = (Lb & 127) >> 1;
    dstP2 = P;
    srcK = (const char*)(kb + bhO) + ((size_t)row*D_ + col)*2;   // + kv0*128B
    srcV = (const char*)(vt + bhO) + ((size_t)row*T_ + col)*2;   // + kv0*2B
  }

  for (int half = 0; half < 2; ++half) {
    const int qt = half ? pidx : (15 - pidx);
    const int q0 = qt * 128;
    const int q0w = q0 + w*16;             // this wave's 16 q rows

    bf16x8 aq[2];
#pragma unroll
    for (int kc = 0; kc < 2; ++kc)
      aq[kc] = *(const bf16x8*)(qb + bhO + (size_t)(q0w + c)*D_ + kc*32 + g*8);

    f32x4 po[4];
    f32x4 ls;
    float mrun = -1e30f;
#pragma unroll
    for (int nd = 0; nd < 4; ++nd) po[nd] = (f32x4){0.f,0.f,0.f,0.f};
    ls = (f32x4){0.f,0.f,0.f,0.f};

    const int nkt = (q0 + 128) >> 6;       // = 2(qt+1), always >= 2

    gld_lds16(srcK, smem + dstP2);
    gld_lds16(srcV, smem + 8192 + dstP2);
    gld_lds16(srcK + (size_t)64*128, smem + 16384 + dstP2);
    gld_lds16(srcV + (size_t)64*2,   smem + 16384 + 8192 + dstP2);
    asm volatile("s_waitcnt vmcnt(2)" ::: "memory");
    __builtin_amdgcn_s_barrier();
    __builtin_amdgcn_sched_barrier(0);

    int rd = 0;                            // buffer index = it % 3
    for (int it = 0; it < nkt; ++it) {
      const int kv0 = it * 64;
      const int cur = rd * 16384;

      if (it + 2 < nkt) {
        int wi = rd + 2; if (wi >= 3) wi -= 3;
        const int wb = wi * 16384;
        gld_lds16(srcK + (size_t)(kv0 + 128) * 128, smem + wb + dstP2);
        gld_lds16(srcV + (size_t)(kv0 + 128) * 2,   smem + wb + 8192 + dstP2);
      }

      if (kv0 < q0w + 16) {
        f32x4 st[4];
#pragma unroll
        for (int ni = 0; ni < 4; ++ni) st[ni] = (f32x4){0.f,0.f,0.f,0.f};
        __builtin_amdgcn_s_setprio(1);
#pragma unroll
        for (int kk = 0; kk < 2; ++kk) {
          bf16x8 bk[4];
#pragma unroll
          for (int ni = 0; ni < 4; ++ni) {
            int kn = ni*16 + c;
            int Lb = kn*128 + (kk*32 + g*8)*2;
            bk[ni] = *(const bf16x8*)(smem + cur + (Lb ^ ((kn & 7) << 4)));
          }
#pragma unroll
          for (int ni = 0; ni < 4; ++ni)
            st[ni] = __builtin_amdgcn_mfma_f32_16x16x32_bf16(bk[ni], aq[kk], st[ni], 0, 0, 0);
        }
        __builtin_amdgcn_s_setprio(0);

        if (kv0 + 64 > q0w) {
          const int qq = q0w + c;
#pragma unroll
          for (int ni = 0; ni < 4; ++ni)
#pragma unroll
            for (int r = 0; r < 4; ++r) {
              int kvv = kv0 + ni*16 + g*4 + r;
              if (kvv > qq) st[ni][r] = -1e30f;
            }
        }

        {
          float mn[4];
#pragma unroll
          for (int ni = 0; ni < 4; ++ni)
            mn[ni] = fmaxf(fmaxf(st[ni][0], st[ni][1]), fmaxf(st[ni][2], st[ni][3]));
          float mt = fmaxf(fmaxf(mn[0], mn[1]), fmaxf(mn[2], mn[3]));
          mt = fmaxf(mt, __shfl_xor(mt, 16));
          mt = fmaxf(mt, __shfl_xor(mt, 32));
          float m_use = mrun;
          if (__any(mt > m_use + 8.f)) {
            float mnew = fmaxf(m_use, mt);
            float alpha = exp2_fast(m_use - mnew);
            mrun = mnew;
            m_use = mnew;
#pragma unroll
            for (int r = 0; r < 4; ++r) ls[r] *= alpha;
#pragma unroll
            for (int nd = 0; nd < 4; ++nd)
#pragma unroll
              for (int r = 0; r < 4; ++r) po[nd][r] *= alpha;
          }
#pragma unroll
          for (int ni = 0; ni < 4; ++ni)
#pragma unroll
            for (int r = 0; r < 4; ++r)
              st[ni][r] = exp2_fast(st[ni][r] - m_use);
        }

        {
          const int row = c;
          const int sw = (row & 7) << 4;
          const int rb = pbase + row*128;
#pragma unroll
          for (int ni = 0; ni < 4; ++ni) {
            unsigned u0, u1;
            asm("v_cvt_pk_bf16_f32 %0, %1, %2" : "=v"(u0) : "v"(st[ni][0]), "v"(st[ni][1]));
            asm("v_cvt_pk_bf16_f32 %0, %1, %2" : "=v"(u1) : "v"(st[ni][2]), "v"(st[ni][3]));
            int Lb = (ni*16 + g*4) * 2;
            uint2 uu; uu.x = u0; uu.y = u1;
            *(uint2*)(smem + rb + (Lb ^ sw)) = uu;
          }
        }

        __builtin_amdgcn_s_setprio(1);
#pragma unroll
        for (int kk = 0; kk < 2; ++kk) {
          bf16x8 pb;
          {
            int pr = c;
            int Lb = pr*128 + (kk*32 + g*8)*2;
            pb = *(const bf16x8*)(smem + pbase + (Lb ^ ((pr & 7) << 4)));
          }
          ls = __builtin_amdgcn_mfma_f32_16x16x32_bf16(vones, pb, ls, 0, 0, 0);
          bf16x8 bv[4];
#pragma unroll
          for (int nd = 0; nd < 4; ++nd) {
            int vr = nd*16 + c;
            int Lb = vr*128 + (kk*32 + g*8)*2;
            bv[nd] = *(const bf16x8*)(smem + cur + 8192 + (Lb ^ ((vr & 7) << 4)));
          }
#pragma unroll
          for (int nd = 0; nd < 4; ++nd)
            po[nd] = __builtin_amdgcn_mfma_f32_16x16x32_bf16(bv[nd], pb, po[nd], 0, 0, 0);
        }
        __builtin_amdgcn_s_setprio(0);
      }

      if (it + 1 < nkt) {
        if (it + 2 < nkt) { asm volatile("s_waitcnt vmcnt(2)" ::: "memory"); }
        else              { asm volatile("s_waitcnt vmcnt(0)" ::: "memory"); }
      }
      __builtin_amdgcn_s_barrier();
      __builtin_amdgcn_sched_barrier(0);
      rd = (rd == 2) ? 0 : rd + 1;
    }

    {
      float inv = 1.f / ls[0];
      int t = q0w + c;
#pragma unroll
      for (int nd = 0; nd < 4; ++nd) {
        ushort4 o;
        o.x = f2bf(po[nd][0] * inv);
        o.y = f2bf(po[nd][1] * inv);
        o.z = f2bf(po[nd][2] * inv);
        o.w = f2bf(po[nd][3] * inv);
        *(ushort4*)(yb + ((size_t)b*T_ + t)*C_ + h*64 + nd*16 + g*4) = o;
      }
    }
  }
}

// ---------------------------------------------------------------- launcher
extern "C" void kernel_launch(void* const* d_in, const int* in_sizes, int n_in,
                              void* d_out, int out_size, void* d_ws, size_t ws_size,
                              hipStream_t stream)
{
  const float* x  = (const float*)d_in[0];
  const float* Wq = (const float*)d_in[1];
  const float* Wk = (const float*)d_in[2];
  const float* Wv = (const float*)d_in[3];
  const float* Wp = (const float*)d_in[4];
  const int*   sp = (const int*)d_in[5];
  float* out = (float*)d_out;

  char* ws = (char*)d_ws;
  unsigned short* xb   = (unsigned short*)(ws);                  // 16 MB
  unsigned short* wcat = (unsigned short*)(ws + 16777216);       // 6 MB [Wq;Wk;Wv]
  unsigned short* wpb  = (unsigned short*)(ws + 23068672);       // 2 MB
  unsigned short* qb   = (unsigned short*)(ws + 25165824);       // 16 MB (B,H,T,D)
  unsigned short* kb   = (unsigned short*)(ws + 41943040);       // 16 MB (B,H,T,D)
  unsigned short* vt   = (unsigned short*)(ws + 58720256);       // 16 MB (B,H,D,T)
  unsigned short* yb   = (unsigned short*)(ws + 75497472);       // 16 MB (B*T, C)
  float* cosT = (float*)(ws + 92274688);                         // 512 KB [T][D]
  float* sinT = (float*)(ws + 92798976);                         // 512 KB [T][D]

  k_convert<<<dim3(2048), dim3(256), 0, stream>>>(x, Wq, Wk, Wv, Wp, xb, wcat, wpb);
  k_rope_tab<<<dim3(512), dim3(256), 0, stream>>>(sp, cosT, sinT);
  k_gemm256<<<dim3(32, 12), dim3(1024), 0, stream>>>(xb, wcat, qb, kb, vt, cosT, sinT);
  k_attn<<<dim3(64, 8), dim3(512), 0, stream>>>(qb, kb, vt, yb);
  k_gemm1<<<dim3(64, 8), dim3(512), 0, stream>>>(yb, wpb, out);
}

// Round 20
// 162.023 us; speedup vs baseline: 1.0532x; 1.0532x over previous
//
#include <hip/hip_runtime.h>
#include <hip/hip_bf16.h>
#include <stdint.h>

// Problem constants
#define B_  4
#define T_  2048
#define C_  1024
#define H_  16
#define D_  64
#define BT  (B_*T_)     // 8192
#define KDIM 1024

typedef __attribute__((ext_vector_type(8))) short bf16x8;
typedef __attribute__((ext_vector_type(4))) float f32x4;

__device__ __forceinline__ unsigned short f2bf(float f) {
  union { float f; unsigned u; } v; v.f = f;
  unsigned r = v.u + 0x7FFFu + ((v.u >> 16) & 1u);   // RNE
  return (unsigned short)(r >> 16);
}

__device__ __forceinline__ float exp2_fast(float x) {   // raw v_exp_f32 (2^x)
  float r;
  asm("v_exp_f32 %0, %1" : "=v"(r) : "v"(x));
  return r;
}

// async global->LDS, 16B per lane. dest must be wave-uniform base + lane*16 (linear).
__device__ __forceinline__ void gld_lds16(const void* g, void* l) {
  __builtin_amdgcn_global_load_lds(
      (__attribute__((address_space(1))) unsigned int*)(uintptr_t)g,
      (__attribute__((address_space(3))) unsigned int*)(unsigned)(uintptr_t)l,
      16, 0, 0);
}

// ---------------------------------------------------------------- prep kernels
__global__ __launch_bounds__(256) void k_convert(
    const float* __restrict__ x,  const float* __restrict__ wq,
    const float* __restrict__ wk, const float* __restrict__ wv,
    const float* __restrict__ wp,
    unsigned short* __restrict__ xb, unsigned short* __restrict__ wcat,
    unsigned short* __restrict__ wpb)
{
  const int NX = BT*C_/4;       // 2097152 float4s of x
  const int NW = C_*C_/4;       // 262144 per W
  const int TOT = NX + 4*NW;
  for (int i = blockIdx.x*blockDim.x + threadIdx.x; i < TOT; i += gridDim.x*blockDim.x) {
    const float4* src; unsigned short* dst; int idx;
    if (i < NX)                { src = (const float4*)x;  dst = xb;            idx = i; }
    else {
      int j = i - NX;
      if (j < NW)              { src = (const float4*)wq; dst = wcat;          idx = j; }
      else if (j < 2*NW)       { src = (const float4*)wk; dst = wcat + C_*C_;  idx = j - NW; }
      else if (j < 3*NW)       { src = (const float4*)wv; dst = wcat + 2*C_*C_;idx = j - 2*NW; }
      else                     { src = (const float4*)wp; dst = wpb;           idx = j - 3*NW; }
    }
    float4 v = src[idx];
    ushort4 o; o.x = f2bf(v.x); o.y = f2bf(v.y); o.z = f2bf(v.z); o.w = f2bf(v.w);
    *(ushort4*)(dst + (size_t)idx*4) = o;
  }
}

// RoPE tables [T][D] (coalesced epilogue loads).
__global__ __launch_bounds__(256) void k_rope_tab(
    const int* __restrict__ start_pos, float* __restrict__ cosT, float* __restrict__ sinT)
{
  int i = blockIdx.x*blockDim.x + threadIdx.x;   // [0, T_*64)
  if (i >= T_*D_) return;
  int t = i >> 6, j = i & 63;
  float inv = exp2f(-(float)(j & 31) * (13.287712379549449f / 32.0f));
  float ang = (float)(t + start_pos[0]) * inv;
  cosT[i] = cosf(ang);
  sinT[i] = sinf(ang);
}

// ---------------------------------------------------------------- 256x192 16-wave GEMM (QKV + RoPE)
// Tail-free grid: BN 256->192 -> grid (32,16) = 512 blocks = 2 EXACT rounds on
// 256 CUs (was 384 blocks = 1.5 ragged rounds = 75% util).
// 16 waves (4M x 4N), wave tile 64x48 -> acc[4][3] = 48 AGPR; ~108 total regs
// <= 128 -> 4 waves/SIMD (R17-proven bin). BK=64.
// LDS per parity: A 32KB (256 rows) + B 24KB (192 rows), stride 57344; dbuf
// 112KB -> 1 block/CU (16 waves resident). Unit layout (proven, 0 conflicts):
// [rows][128B], byte = row*128 + (kc*2 ^ ((row&7)<<4)).
// Staging per tile: A = 2 loads/thread; B = 1 load/thread + 1 extra for waves
// 0..7 (tid<512; wave-uniform predicate -> safe with global_load_lds).
// Schedule: ONE __syncthreads per K-tile; stage t+1 right after (drain is a
// full tile old at the next sync -> no vmcnt stall).
__global__ __launch_bounds__(1024, 4) void k_gemm256(
    const unsigned short* __restrict__ A, const unsigned short* __restrict__ Bw,
    unsigned short* __restrict__ qb, unsigned short* __restrict__ kb,
    unsigned short* __restrict__ vt,
    const float* __restrict__ cosT, const float* __restrict__ sinT)
{
  __shared__ __attribute__((aligned(16))) char smem[114688];   // 2 x 57344
  const int tid = threadIdx.x, l = tid & 63, w = tid >> 6;     // w in 0..15
  const int g = l >> 4, c = l & 15;
  const int m0 = blockIdx.x * 256, n0 = blockIdx.y * 192;
  const int wr = w >> 2, wc = w & 3;
  const char* gA = (const char*)A;
  const char* gB = (const char*)Bw;

  // A staging: 32KB = 2048 chunks, 2 per thread. Inverse of unit layout.
  int dstA[2]; size_t aoff[2];
#pragma unroll
  for (int j = 0; j < 2; ++j) {
    int P = j*16384 + tid*16;
    int row = P >> 7;                        // 0..255
    int kc = ((P & 127) ^ ((row & 7) << 4)) >> 1;
    dstA[j] = P;
    aoff[j] = ((size_t)(m0 + row) * KDIM + kc) * 2;
  }
  // B staging: 24KB = 1536 chunks: all threads chunk tid; tid<512 also 1024+tid.
  int dstB[2]; size_t boff[2];
#pragma unroll
  for (int j = 0; j < 2; ++j) {
    int P = (j == 0) ? tid*16 : (16384 + tid*16);   // j=1 valid only tid<512
    int row = P >> 7;                        // 0..191 (for valid range)
    int kc = ((P & 127) ^ ((row & 7) << 4)) >> 1;
    dstB[j] = P;
    boff[j] = ((size_t)(n0 + row) * KDIM + kc) * 2;
  }
  const bool bsec = (tid < 512);

  // frag-read constants: row&7 == c&7 (48 and 16 are multiples of 8)
  const int aB = (wr*64 + c) * 128;            // + par + mi*2048 + xt
  const int bB = 32768 + (wc*48 + c) * 128;    // + par + ni*2048 + xt
  const int xsw = (c & 7) << 4;

  f32x4 acc[4][3];
#pragma unroll
  for (int i = 0; i < 4; ++i)
#pragma unroll
    for (int j = 0; j < 3; ++j) acc[i][j] = (f32x4){0.f,0.f,0.f,0.f};

  // prologue: stage tile 0 into parity 0
#pragma unroll
  for (int j = 0; j < 2; ++j) gld_lds16(gA + aoff[j], smem + dstA[j]);
  gld_lds16(gB + boff[0], smem + 32768 + dstB[0]);
  if (bsec) gld_lds16(gB + boff[1], smem + 32768 + dstB[1]);

  for (int t = 0; t < 16; ++t) {
    const int par = (t & 1) ? 57344 : 0;
    const int nxt = (t & 1) ? 0 : 57344;

    __syncthreads();   // drains last tile's stages (full tile old) + orders LDS

    if (t + 1 < 16) {
      const size_t ko = (size_t)(t + 1) * 128;
#pragma unroll
      for (int j = 0; j < 2; ++j) gld_lds16(gA + aoff[j] + ko, smem + nxt + dstA[j]);
      gld_lds16(gB + boff[0] + ko, smem + nxt + 32768 + dstB[0]);
      if (bsec) gld_lds16(gB + boff[1] + ko, smem + nxt + 32768 + dstB[1]);
    }

#pragma unroll
    for (int kk = 0; kk < 2; ++kk) {
      const int xt = (kk*64 + g*16) ^ xsw;
      bf16x8 af[4], bk[3];
#pragma unroll
      for (int ni = 0; ni < 3; ++ni)
        bk[ni] = *(const bf16x8*)(smem + par + bB + ni*2048 + xt);
#pragma unroll
      for (int mi = 0; mi < 4; ++mi)
        af[mi] = *(const bf16x8*)(smem + par + aB + mi*2048 + xt);
      __builtin_amdgcn_s_setprio(1);
#pragma unroll
      for (int mi = 0; mi < 4; ++mi)
#pragma unroll
        for (int ni = 0; ni < 3; ++ni)
          acc[mi][ni] = __builtin_amdgcn_mfma_f32_16x16x32_bf16(af[mi], bk[ni], acc[mi][ni], 0, 0, 0);
      __builtin_amdgcn_s_setprio(0);
    }
  }

  // epilogue: fused RoPE; C layout: col = lane&15, row = g*4 + r
  // 'which' is fragment-uniform: fragment col base and 1024-boundaries are both
  // multiples of 16, so a 16-wide fragment never straddles q/k/v.
#pragma unroll
  for (int mi = 0; mi < 4; ++mi) {
#pragma unroll
    for (int ni = 0; ni < 3; ++ni) {
      const int mrow0 = m0 + wr*64 + mi*16 + g*4;
      const int ncol  = n0 + wc*48 + ni*16 + c;
      const int which = ncol >> 10;          // 0=q 1=k 2=v
      const int d = ncol & 1023, h = d >> 6, dd = d & 63;
      const int b = mrow0 >> 11, t0 = mrow0 & 2047;
      if (which == 2) {
        ushort4 o;
        o.x = f2bf(acc[mi][ni][0]); o.y = f2bf(acc[mi][ni][1]);
        o.z = f2bf(acc[mi][ni][2]); o.w = f2bf(acc[mi][ni][3]);
        *(ushort4*)(vt + ((size_t)((b*H_ + h)*D_ + dd))*T_ + t0) = o;
      } else {
#pragma unroll
        for (int r = 0; r < 4; ++r) {
          float val = acc[mi][ni][r];
          float partner = __shfl_xor(val, 1);          // value at dd^1 (lane^1)
          float rot = (dd & 1) ? partner : -partner;   // interleaved rotate_half
          float cv = cosT[(t0 + r)*64 + dd], sv = sinT[(t0 + r)*64 + dd];
          float o = val*cv + rot*sv;
          size_t oidx = (((size_t)(b*H_ + h))*T_ + (t0 + r))*D_ + dd;
          // q pre-scale: 1/sqrt(64) * log2(e)  (softmax done in exp2 domain)
          if (which == 0) qb[oidx] = f2bf(o * 0.180336879f);
          else            kb[oidx] = f2bf(o);
        }
      }
    }
  }
}

// ---------------------------------------------------------------- output-projection GEMM, 128x128, 8 waves
// (unchanged from R19 passing kernel: acc[4][2]=32 AGPR, 4 waves/SIMD, 64KB LDS)
__global__ __launch_bounds__(512, 4) void k_gemm1(
    const unsigned short* __restrict__ A, const unsigned short* __restrict__ Bw,
    float* __restrict__ outF)
{
  __shared__ __attribute__((aligned(16))) char smem[65536];
  const int tid = threadIdx.x, l = tid & 63, w = tid >> 6;   // w in 0..7
  const int g = l >> 4, c = l & 15;
  const int m0 = blockIdx.x * 128, n0 = blockIdx.y * 128;
  const int wr = w >> 2, wc = w & 3;
  const char* gA = (const char*)A;
  const char* gB = (const char*)Bw;

  int dstP[2]; size_t aoff[2], boff[2];
#pragma unroll
  for (int j = 0; j < 2; ++j) {
    int P = j*8192 + tid*16;                 // [0, 16384)
    int row = P >> 7;                        // 0..127
    int kc = ((P & 127) ^ ((row & 7) << 4)) >> 1;
    dstP[j] = P;
    aoff[j] = ((size_t)(m0 + row) * KDIM + kc) * 2;
    boff[j] = ((size_t)(n0 + row) * KDIM + kc) * 2;
  }

  const int aB = (wr*64 + c) * 128;            // + par + mi*2048 + xt   (4 mi)
  const int bB = 16384 + (wc*32 + c) * 128;    // + par + ni*2048 + xt   (2 ni)
  const int xsw = (c & 7) << 4;

  f32x4 acc[4][2];
#pragma unroll
  for (int i = 0; i < 4; ++i)
#pragma unroll
    for (int j = 0; j < 2; ++j) acc[i][j] = (f32x4){0.f,0.f,0.f,0.f};

#pragma unroll
  for (int j = 0; j < 2; ++j) {
    gld_lds16(gA + aoff[j], smem + dstP[j]);
    gld_lds16(gB + boff[j], smem + 16384 + dstP[j]);
  }

  for (int t = 0; t < 16; ++t) {
    const int par = (t & 1) << 15;           // 0 or 32768
    const int nxt = par ^ 32768;

    __syncthreads();

    if (t + 1 < 16) {
      const size_t ko = (size_t)(t + 1) * 128;   // +64 bf16 along K
#pragma unroll
      for (int j = 0; j < 2; ++j) {
        gld_lds16(gA + aoff[j] + ko, smem + nxt + dstP[j]);
        gld_lds16(gB + boff[j] + ko, smem + nxt + 16384 + dstP[j]);
      }
    }

#pragma unroll
    for (int kk = 0; kk < 2; ++kk) {
      const int xt = (kk*64 + g*16) ^ xsw;
      bf16x8 af[4], bk[2];
#pragma unroll
      for (int ni = 0; ni < 2; ++ni)
        bk[ni] = *(const bf16x8*)(smem + par + bB + ni*2048 + xt);
#pragma unroll
      for (int mi = 0; mi < 4; ++mi)
        af[mi] = *(const bf16x8*)(smem + par + aB + mi*2048 + xt);
      __builtin_amdgcn_s_setprio(1);
#pragma unroll
      for (int mi = 0; mi < 4; ++mi)
#pragma unroll
        for (int ni = 0; ni < 2; ++ni)
          acc[mi][ni] = __builtin_amdgcn_mfma_f32_16x16x32_bf16(af[mi], bk[ni], acc[mi][ni], 0, 0, 0);
      __builtin_amdgcn_s_setprio(0);
    }
  }

#pragma unroll
  for (int mi = 0; mi < 4; ++mi) {
#pragma unroll
    for (int ni = 0; ni < 2; ++ni) {
      const int mrow0 = m0 + wr*64 + mi*16 + g*4;
      const int ncol  = n0 + wc*32 + ni*16 + c;
#pragma unroll
      for (int r = 0; r < 4; ++r)
        outF[(size_t)(mrow0 + r) * 1024 + ncol] = acc[mi][ni][r];
    }
  }
}

// ---------------------------------------------------------------- flash attention
// (unchanged from R14-R19 passing kernel: 8 waves x 16 q-rows, XCD grid, 3-deep KV)
__global__ __launch_bounds__(512) void k_attn(
    const unsigned short* __restrict__ qb, const unsigned short* __restrict__ kb,
    const unsigned short* __restrict__ vt, unsigned short* __restrict__ yb)
{
  __shared__ __attribute__((aligned(16))) char smem[65536]; // 3x(K8K+V8K) + P:16K
  const int tid = threadIdx.x, l = tid & 63, w = tid >> 6;  // w in 0..7
  const int g = l >> 4, c = l & 15;
  const int bh = blockIdx.x;                 // x = bh -> XCD locality
  const int pidx = blockIdx.y;               // pair index 0..7
  const size_t bhO = (size_t)bh * T_ * D_;
  const int pbase = 49152 + w*2048;          // per-wave 2 KB P region
  const int b = bh >> 4, h = bh & 15;

  bf16x8 vones;
#pragma unroll
  for (int i = 0; i < 8; ++i) vones[i] = (short)0x3F80;   // bf16 1.0

  const char* srcK; const char* srcV; int dstP2;
  {
    int P = w*1024 + l*16;                 // [0, 8192)
    int row = P >> 7;
    int Lb = P ^ ((row & 7) << 4);
    int col = (Lb & 127) >> 1;
    dstP2 = P;
    srcK = (const char*)(kb + bhO) + ((size_t)row*D_ + col)*2;   // + kv0*128B
    srcV = (const char*)(vt + bhO) + ((size_t)row*T_ + col)*2;   // + kv0*2B
  }

  for (int half = 0; half < 2; ++half) {
    const int qt = half ? pidx : (15 - pidx);
    const int q0 = qt * 128;
    const int q0w = q0 + w*16;             // this wave's 16 q rows

    bf16x8 aq[2];
#pragma unroll
    for (int kc = 0; kc < 2; ++kc)
      aq[kc] = *(const bf16x8*)(qb + bhO + (size_t)(q0w + c)*D_ + kc*32 + g*8);

    f32x4 po[4];
    f32x4 ls;
    float mrun = -1e30f;
#pragma unroll
    for (int nd = 0; nd < 4; ++nd) po[nd] = (f32x4){0.f,0.f,0.f,0.f};
    ls = (f32x4){0.f,0.f,0.f,0.f};

    const int nkt = (q0 + 128) >> 6;       // = 2(qt+1), always >= 2

    gld_lds16(srcK, smem + dstP2);
    gld_lds16(srcV, smem + 8192 + dstP2);
    gld_lds16(srcK + (size_t)64*128, smem + 16384 + dstP2);
    gld_lds16(srcV + (size_t)64*2,   smem + 16384 + 8192 + dstP2);
    asm volatile("s_waitcnt vmcnt(2)" ::: "memory");
    __builtin_amdgcn_s_barrier();
    __builtin_amdgcn_sched_barrier(0);

    int rd = 0;                            // buffer index = it % 3
    for (int it = 0; it < nkt; ++it) {
      const int kv0 = it * 64;
      const int cur = rd * 16384;

      if (it + 2 < nkt) {
        int wi = rd + 2; if (wi >= 3) wi -= 3;
        const int wb = wi * 16384;
        gld_lds16(srcK + (size_t)(kv0 + 128) * 128, smem + wb + dstP2);
        gld_lds16(srcV + (size_t)(kv0 + 128) * 2,   smem + wb + 8192 + dstP2);
      }

      if (kv0 < q0w + 16) {
        f32x4 st[4];
#pragma unroll
        for (int ni = 0; ni < 4; ++ni) st[ni] = (f32x4){0.f,0.f,0.f,0.f};
        __builtin_amdgcn_s_setprio(1);
#pragma unroll
        for (int kk = 0; kk < 2; ++kk) {
          bf16x8 bk[4];
#pragma unroll
          for (int ni = 0; ni < 4; ++ni) {
            int kn = ni*16 + c;
            int Lb = kn*128 + (kk*32 + g*8)*2;
            bk[ni] = *(const bf16x8*)(smem + cur + (Lb ^ ((kn & 7) << 4)));
          }
#pragma unroll
          for (int ni = 0; ni < 4; ++ni)
            st[ni] = __builtin_amdgcn_mfma_f32_16x16x32_bf16(bk[ni], aq[kk], st[ni], 0, 0, 0);
        }
        __builtin_amdgcn_s_setprio(0);

        if (kv0 + 64 > q0w) {
          const int qq = q0w + c;
#pragma unroll
          for (int ni = 0; ni < 4; ++ni)
#pragma unroll
            for (int r = 0; r < 4; ++r) {
              int kvv = kv0 + ni*16 + g*4 + r;
              if (kvv > qq) st[ni][r] = -1e30f;
            }
        }

        {
          float mn[4];
#pragma unroll
          for (int ni = 0; ni < 4; ++ni)
            mn[ni] = fmaxf(fmaxf(st[ni][0], st[ni][1]), fmaxf(st[ni][2], st[ni][3]));
          float mt = fmaxf(fmaxf(mn[0], mn[1]), fmaxf(mn[2], mn[3]));
          mt = fmaxf(mt, __shfl_xor(mt, 16));
          mt = fmaxf(mt, __shfl_xor(mt, 32));
          float m_use = mrun;
          if (__any(mt > m_use + 8.f)) {
            float mnew = fmaxf(m_use, mt);
            float alpha = exp2_fast(m_use - mnew);
            mrun = mnew;
            m_use = mnew;
#pragma unroll
            for (int r = 0; r < 4; ++r) ls[r] *= alpha;
#pragma unroll
            for (int nd = 0; nd < 4; ++nd)
#pragma unroll
              for (int r = 0; r < 4; ++r) po[nd][r] *= alpha;
          }
#pragma unroll
          for (int ni = 0; ni < 4; ++ni)
#pragma unroll
            for (int r = 0; r < 4; ++r)
              st[ni][r] = exp2_fast(st[ni][r] - m_use);
        }

        {
          const int row = c;
          const int sw = (row & 7) << 4;
          const int rb = pbase + row*128;
#pragma unroll
          for (int ni = 0; ni < 4; ++ni) {
            unsigned u0, u1;
            asm("v_cvt_pk_bf16_f32 %0, %1, %2" : "=v"(u0) : "v"(st[ni][0]), "v"(st[ni][1]));
            asm("v_cvt_pk_bf16_f32 %0, %1, %2" : "=v"(u1) : "v"(st[ni][2]), "v"(st[ni][3]));
            int Lb = (ni*16 + g*4) * 2;
            uint2 uu; uu.x = u0; uu.y = u1;
            *(uint2*)(smem + rb + (Lb ^ sw)) = uu;
          }
        }

        __builtin_amdgcn_s_setprio(1);
#pragma unroll
        for (int kk = 0; kk < 2; ++kk) {
          bf16x8 pb;
          {
            int pr = c;
            int Lb = pr*128 + (kk*32 + g*8)*2;
            pb = *(const bf16x8*)(smem + pbase + (Lb ^ ((pr & 7) << 4)));
          }
          ls = __builtin_amdgcn_mfma_f32_16x16x32_bf16(vones, pb, ls, 0, 0, 0);
          bf16x8 bv[4];
#pragma unroll
          for (int nd = 0; nd < 4; ++nd) {
            int vr = nd*16 + c;
            int Lb = vr*128 + (kk*32 + g*8)*2;
            bv[nd] = *(const bf16x8*)(smem + cur + 8192 + (Lb ^ ((vr & 7) << 4)));
          }
#pragma unroll
          for (int nd = 0; nd < 4; ++nd)
            po[nd] = __builtin_amdgcn_mfma_f32_16x16x32_bf16(bv[nd], pb, po[nd], 0, 0, 0);
        }
        __builtin_amdgcn_s_setprio(0);
      }

      if (it + 1 < nkt) {
        if (it + 2 < nkt) { asm volatile("s_waitcnt vmcnt(2)" ::: "memory"); }
        else              { asm volatile("s_waitcnt vmcnt(0)" ::: "memory"); }
      }
      __builtin_amdgcn_s_barrier();
      __builtin_amdgcn_sched_barrier(0);
      rd = (rd == 2) ? 0 : rd + 1;
    }

    {
      float inv = 1.f / ls[0];
      int t = q0w + c;
#pragma unroll
      for (int nd = 0; nd < 4; ++nd) {
        ushort4 o;
        o.x = f2bf(po[nd][0] * inv);
        o.y = f2bf(po[nd][1] * inv);
        o.z = f2bf(po[nd][2] * inv);
        o.w = f2bf(po[nd][3] * inv);
        *(ushort4*)(yb + ((size_t)b*T_ + t)*C_ + h*64 + nd*16 + g*4) = o;
      }
    }
  }
}

// ---------------------------------------------------------------- launcher
extern "C" void kernel_launch(void* const* d_in, const int* in_sizes, int n_in,
                              void* d_out, int out_size, void* d_ws, size_t ws_size,
                              hipStream_t stream)
{
  const float* x  = (const float*)d_in[0];
  const float* Wq = (const float*)d_in[1];
  const float* Wk = (const float*)d_in[2];
  const float* Wv = (const float*)d_in[3];
  const float* Wp = (const float*)d_in[4];
  const int*   sp = (const int*)d_in[5];
  float* out = (float*)d_out;

  char* ws = (char*)d_ws;
  unsigned short* xb   = (unsigned short*)(ws);                  // 16 MB
  unsigned short* wcat = (unsigned short*)(ws + 16777216);       // 6 MB [Wq;Wk;Wv]
  unsigned short* wpb  = (unsigned short*)(ws + 23068672);       // 2 MB
  unsigned short* qb   = (unsigned short*)(ws + 25165824);       // 16 MB (B,H,T,D)
  unsigned short* kb   = (unsigned short*)(ws + 41943040);       // 16 MB (B,H,T,D)
  unsigned short* vt   = (unsigned short*)(ws + 58720256);       // 16 MB (B,H,D,T)
  unsigned short* yb   = (unsigned short*)(ws + 75497472);       // 16 MB (B*T, C)
  float* cosT = (float*)(ws + 92274688);                         // 512 KB [T][D]
  float* sinT = (float*)(ws + 92798976);                         // 512 KB [T][D]

  k_convert<<<dim3(2048), dim3(256), 0, stream>>>(x, Wq, Wk, Wv, Wp, xb, wcat, wpb);
  k_rope_tab<<<dim3(512), dim3(256), 0, stream>>>(sp, cosT, sinT);
  k_gemm256<<<dim3(32, 16), dim3(1024), 0, stream>>>(xb, wcat, qb, kb, vt, cosT, sinT);
  k_attn<<<dim3(64, 8), dim3(512), 0, stream>>>(qb, kb, vt, yb);
  k_gemm1<<<dim3(64, 8), dim3(512), 0, stream>>>(yb, wpb, out);
}

// Round 21
// 161.027 us; speedup vs baseline: 1.0597x; 1.0062x over previous
//
#include <hip/hip_runtime.h>
#include <hip/hip_bf16.h>
#include <stdint.h>

// Problem constants
#define B_  4
#define T_  2048
#define C_  1024
#define H_  16
#define D_  64
#define BT  (B_*T_)     // 8192
#define KDIM 1024

typedef __attribute__((ext_vector_type(8))) short bf16x8;
typedef __attribute__((ext_vector_type(4))) float f32x4;

__device__ __forceinline__ unsigned short f2bf(float f) {
  union { float f; unsigned u; } v; v.f = f;
  unsigned r = v.u + 0x7FFFu + ((v.u >> 16) & 1u);   // RNE
  return (unsigned short)(r >> 16);
}

__device__ __forceinline__ float exp2_fast(float x) {   // raw v_exp_f32 (2^x)
  float r;
  asm("v_exp_f32 %0, %1" : "=v"(r) : "v"(x));
  return r;
}

// async global->LDS, 16B per lane. dest must be wave-uniform base + lane*16 (linear).
__device__ __forceinline__ void gld_lds16(const void* g, void* l) {
  __builtin_amdgcn_global_load_lds(
      (__attribute__((address_space(1))) unsigned int*)(uintptr_t)g,
      (__attribute__((address_space(3))) unsigned int*)(unsigned)(uintptr_t)l,
      16, 0, 0);
}

// ---------------------------------------------------------------- prep kernels
__global__ __launch_bounds__(256) void k_convert(
    const float* __restrict__ x,  const float* __restrict__ wq,
    const float* __restrict__ wk, const float* __restrict__ wv,
    const float* __restrict__ wp,
    unsigned short* __restrict__ xb, unsigned short* __restrict__ wcat,
    unsigned short* __restrict__ wpb)
{
  const int NX = BT*C_/4;       // 2097152 float4s of x
  const int NW = C_*C_/4;       // 262144 per W
  const int TOT = NX + 4*NW;
  for (int i = blockIdx.x*blockDim.x + threadIdx.x; i < TOT; i += gridDim.x*blockDim.x) {
    const float4* src; unsigned short* dst; int idx;
    if (i < NX)                { src = (const float4*)x;  dst = xb;            idx = i; }
    else {
      int j = i - NX;
      if (j < NW)              { src = (const float4*)wq; dst = wcat;          idx = j; }
      else if (j < 2*NW)       { src = (const float4*)wk; dst = wcat + C_*C_;  idx = j - NW; }
      else if (j < 3*NW)       { src = (const float4*)wv; dst = wcat + 2*C_*C_;idx = j - 2*NW; }
      else                     { src = (const float4*)wp; dst = wpb;           idx = j - 3*NW; }
    }
    float4 v = src[idx];
    ushort4 o; o.x = f2bf(v.x); o.y = f2bf(v.y); o.z = f2bf(v.z); o.w = f2bf(v.w);
    *(ushort4*)(dst + (size_t)idx*4) = o;
  }
}

// RoPE tables [T][D] (coalesced epilogue loads).
__global__ __launch_bounds__(256) void k_rope_tab(
    const int* __restrict__ start_pos, float* __restrict__ cosT, float* __restrict__ sinT)
{
  int i = blockIdx.x*blockDim.x + threadIdx.x;   // [0, T_*64)
  if (i >= T_*D_) return;
  int t = i >> 6, j = i & 63;
  float inv = exp2f(-(float)(j & 31) * (13.287712379549449f / 32.0f));
  float ang = (float)(t + start_pos[0]) * inv;
  cosT[i] = cosf(ang);
  sinT[i] = sinf(ang);
}

// ---------------------------------------------------------------- 256x192 16-wave GEMM (QKV + RoPE)
// (unchanged from R20 passing kernel: tail-free grid (32,16)=512 blocks,
// 16 waves, wave tile 64x48 = 48 AGPR, 4 waves/SIMD)
__global__ __launch_bounds__(1024, 4) void k_gemm256(
    const unsigned short* __restrict__ A, const unsigned short* __restrict__ Bw,
    unsigned short* __restrict__ qb, unsigned short* __restrict__ kb,
    unsigned short* __restrict__ vt,
    const float* __restrict__ cosT, const float* __restrict__ sinT)
{
  __shared__ __attribute__((aligned(16))) char smem[114688];   // 2 x 57344
  const int tid = threadIdx.x, l = tid & 63, w = tid >> 6;     // w in 0..15
  const int g = l >> 4, c = l & 15;
  const int m0 = blockIdx.x * 256, n0 = blockIdx.y * 192;
  const int wr = w >> 2, wc = w & 3;
  const char* gA = (const char*)A;
  const char* gB = (const char*)Bw;

  // A staging: 32KB = 2048 chunks, 2 per thread. Inverse of unit layout.
  int dstA[2]; size_t aoff[2];
#pragma unroll
  for (int j = 0; j < 2; ++j) {
    int P = j*16384 + tid*16;
    int row = P >> 7;                        // 0..255
    int kc = ((P & 127) ^ ((row & 7) << 4)) >> 1;
    dstA[j] = P;
    aoff[j] = ((size_t)(m0 + row) * KDIM + kc) * 2;
  }
  // B staging: 24KB = 1536 chunks: all threads chunk tid; tid<512 also 1024+tid.
  int dstB[2]; size_t boff[2];
#pragma unroll
  for (int j = 0; j < 2; ++j) {
    int P = (j == 0) ? tid*16 : (16384 + tid*16);   // j=1 valid only tid<512
    int row = P >> 7;                        // 0..191 (for valid range)
    int kc = ((P & 127) ^ ((row & 7) << 4)) >> 1;
    dstB[j] = P;
    boff[j] = ((size_t)(n0 + row) * KDIM + kc) * 2;
  }
  const bool bsec = (tid < 512);

  // frag-read constants: row&7 == c&7 (48 and 16 are multiples of 8)
  const int aB = (wr*64 + c) * 128;            // + par + mi*2048 + xt
  const int bB = 32768 + (wc*48 + c) * 128;    // + par + ni*2048 + xt
  const int xsw = (c & 7) << 4;

  f32x4 acc[4][3];
#pragma unroll
  for (int i = 0; i < 4; ++i)
#pragma unroll
    for (int j = 0; j < 3; ++j) acc[i][j] = (f32x4){0.f,0.f,0.f,0.f};

  // prologue: stage tile 0 into parity 0
#pragma unroll
  for (int j = 0; j < 2; ++j) gld_lds16(gA + aoff[j], smem + dstA[j]);
  gld_lds16(gB + boff[0], smem + 32768 + dstB[0]);
  if (bsec) gld_lds16(gB + boff[1], smem + 32768 + dstB[1]);

  for (int t = 0; t < 16; ++t) {
    const int par = (t & 1) ? 57344 : 0;
    const int nxt = (t & 1) ? 0 : 57344;

    __syncthreads();   // drains last tile's stages (full tile old) + orders LDS

    if (t + 1 < 16) {
      const size_t ko = (size_t)(t + 1) * 128;
#pragma unroll
      for (int j = 0; j < 2; ++j) gld_lds16(gA + aoff[j] + ko, smem + nxt + dstA[j]);
      gld_lds16(gB + boff[0] + ko, smem + nxt + 32768 + dstB[0]);
      if (bsec) gld_lds16(gB + boff[1] + ko, smem + nxt + 32768 + dstB[1]);
    }

#pragma unroll
    for (int kk = 0; kk < 2; ++kk) {
      const int xt = (kk*64 + g*16) ^ xsw;
      bf16x8 af[4], bk[3];
#pragma unroll
      for (int ni = 0; ni < 3; ++ni)
        bk[ni] = *(const bf16x8*)(smem + par + bB + ni*2048 + xt);
#pragma unroll
      for (int mi = 0; mi < 4; ++mi)
        af[mi] = *(const bf16x8*)(smem + par + aB + mi*2048 + xt);
      __builtin_amdgcn_s_setprio(1);
#pragma unroll
      for (int mi = 0; mi < 4; ++mi)
#pragma unroll
        for (int ni = 0; ni < 3; ++ni)
          acc[mi][ni] = __builtin_amdgcn_mfma_f32_16x16x32_bf16(af[mi], bk[ni], acc[mi][ni], 0, 0, 0);
      __builtin_amdgcn_s_setprio(0);
    }
  }

  // epilogue: fused RoPE; C layout: col = lane&15, row = g*4 + r
#pragma unroll
  for (int mi = 0; mi < 4; ++mi) {
#pragma unroll
    for (int ni = 0; ni < 3; ++ni) {
      const int mrow0 = m0 + wr*64 + mi*16 + g*4;
      const int ncol  = n0 + wc*48 + ni*16 + c;
      const int which = ncol >> 10;          // 0=q 1=k 2=v
      const int d = ncol & 1023, h = d >> 6, dd = d & 63;
      const int b = mrow0 >> 11, t0 = mrow0 & 2047;
      if (which == 2) {
        ushort4 o;
        o.x = f2bf(acc[mi][ni][0]); o.y = f2bf(acc[mi][ni][1]);
        o.z = f2bf(acc[mi][ni][2]); o.w = f2bf(acc[mi][ni][3]);
        *(ushort4*)(vt + ((size_t)((b*H_ + h)*D_ + dd))*T_ + t0) = o;
      } else {
#pragma unroll
        for (int r = 0; r < 4; ++r) {
          float val = acc[mi][ni][r];
          float partner = __shfl_xor(val, 1);          // value at dd^1 (lane^1)
          float rot = (dd & 1) ? partner : -partner;   // interleaved rotate_half
          float cv = cosT[(t0 + r)*64 + dd], sv = sinT[(t0 + r)*64 + dd];
          float o = val*cv + rot*sv;
          size_t oidx = (((size_t)(b*H_ + h))*T_ + (t0 + r))*D_ + dd;
          // q pre-scale: 1/sqrt(64) * log2(e)  (softmax done in exp2 domain)
          if (which == 0) qb[oidx] = f2bf(o * 0.180336879f);
          else            kb[oidx] = f2bf(o);
        }
      }
    }
  }
}

// ---------------------------------------------------------------- output-projection GEMM, 128x128, 8 waves
// (unchanged from R19/R20 passing kernel)
__global__ __launch_bounds__(512, 4) void k_gemm1(
    const unsigned short* __restrict__ A, const unsigned short* __restrict__ Bw,
    float* __restrict__ outF)
{
  __shared__ __attribute__((aligned(16))) char smem[65536];
  const int tid = threadIdx.x, l = tid & 63, w = tid >> 6;   // w in 0..7
  const int g = l >> 4, c = l & 15;
  const int m0 = blockIdx.x * 128, n0 = blockIdx.y * 128;
  const int wr = w >> 2, wc = w & 3;
  const char* gA = (const char*)A;
  const char* gB = (const char*)Bw;

  int dstP[2]; size_t aoff[2], boff[2];
#pragma unroll
  for (int j = 0; j < 2; ++j) {
    int P = j*8192 + tid*16;                 // [0, 16384)
    int row = P >> 7;                        // 0..127
    int kc = ((P & 127) ^ ((row & 7) << 4)) >> 1;
    dstP[j] = P;
    aoff[j] = ((size_t)(m0 + row) * KDIM + kc) * 2;
    boff[j] = ((size_t)(n0 + row) * KDIM + kc) * 2;
  }

  const int aB = (wr*64 + c) * 128;            // + par + mi*2048 + xt   (4 mi)
  const int bB = 16384 + (wc*32 + c) * 128;    // + par + ni*2048 + xt   (2 ni)
  const int xsw = (c & 7) << 4;

  f32x4 acc[4][2];
#pragma unroll
  for (int i = 0; i < 4; ++i)
#pragma unroll
    for (int j = 0; j < 2; ++j) acc[i][j] = (f32x4){0.f,0.f,0.f,0.f};

#pragma unroll
  for (int j = 0; j < 2; ++j) {
    gld_lds16(gA + aoff[j], smem + dstP[j]);
    gld_lds16(gB + boff[j], smem + 16384 + dstP[j]);
  }

  for (int t = 0; t < 16; ++t) {
    const int par = (t & 1) << 15;           // 0 or 32768
    const int nxt = par ^ 32768;

    __syncthreads();

    if (t + 1 < 16) {
      const size_t ko = (size_t)(t + 1) * 128;   // +64 bf16 along K
#pragma unroll
      for (int j = 0; j < 2; ++j) {
        gld_lds16(gA + aoff[j] + ko, smem + nxt + dstP[j]);
        gld_lds16(gB + boff[j] + ko, smem + nxt + 16384 + dstP[j]);
      }
    }

#pragma unroll
    for (int kk = 0; kk < 2; ++kk) {
      const int xt = (kk*64 + g*16) ^ xsw;
      bf16x8 af[4], bk[2];
#pragma unroll
      for (int ni = 0; ni < 2; ++ni)
        bk[ni] = *(const bf16x8*)(smem + par + bB + ni*2048 + xt);
#pragma unroll
      for (int mi = 0; mi < 4; ++mi)
        af[mi] = *(const bf16x8*)(smem + par + aB + mi*2048 + xt);
      __builtin_amdgcn_s_setprio(1);
#pragma unroll
      for (int mi = 0; mi < 4; ++mi)
#pragma unroll
        for (int ni = 0; ni < 2; ++ni)
          acc[mi][ni] = __builtin_amdgcn_mfma_f32_16x16x32_bf16(af[mi], bk[ni], acc[mi][ni], 0, 0, 0);
      __builtin_amdgcn_s_setprio(0);
    }
  }

#pragma unroll
  for (int mi = 0; mi < 4; ++mi) {
#pragma unroll
    for (int ni = 0; ni < 2; ++ni) {
      const int mrow0 = m0 + wr*64 + mi*16 + g*4;
      const int ncol  = n0 + wc*32 + ni*16 + c;
#pragma unroll
      for (int r = 0; r < 4; ++r)
        outF[(size_t)(mrow0 + r) * 1024 + ncol] = acc[mi][ni][r];
    }
  }
}

// ---------------------------------------------------------------- flash attention
// R20 structure with 2-deep KV buffering (was 3-deep): LDS 64KB -> 48KB ->
// 3 blocks/CU = 24 waves/CU = 6 waves/SIMD (+50% TLP; R10->R11 showed the 3rd
// buffer's extra latency-hiding was not on the critical path).
// Schedule per iter i: {stage tile i+1 -> buf[(i+1)%2]} (that buffer's readers
// all retired at the END barrier of iter i-1); compute buf[i%2]; vmcnt(0)
// (drains the stage issued at iter-top, ~1500cyc old -> cheap); barrier.
__global__ __launch_bounds__(512) void k_attn(
    const unsigned short* __restrict__ qb, const unsigned short* __restrict__ kb,
    const unsigned short* __restrict__ vt, unsigned short* __restrict__ yb)
{
  __shared__ __attribute__((aligned(16))) char smem[49152]; // 2x(K8K+V8K) + P:16K
  const int tid = threadIdx.x, l = tid & 63, w = tid >> 6;  // w in 0..7
  const int g = l >> 4, c = l & 15;
  const int bh = blockIdx.x;                 // x = bh -> XCD locality
  const int pidx = blockIdx.y;               // pair index 0..7
  const size_t bhO = (size_t)bh * T_ * D_;
  const int pbase = 32768 + w*2048;          // per-wave 2 KB P region
  const int b = bh >> 4, h = bh & 15;

  bf16x8 vones;
#pragma unroll
  for (int i = 0; i < 8; ++i) vones[i] = (short)0x3F80;   // bf16 1.0

  const char* srcK; const char* srcV; int dstP2;
  {
    int P = w*1024 + l*16;                 // [0, 8192)
    int row = P >> 7;
    int Lb = P ^ ((row & 7) << 4);
    int col = (Lb & 127) >> 1;
    dstP2 = P;
    srcK = (const char*)(kb + bhO) + ((size_t)row*D_ + col)*2;   // + kv0*128B
    srcV = (const char*)(vt + bhO) + ((size_t)row*T_ + col)*2;   // + kv0*2B
  }

  for (int half = 0; half < 2; ++half) {
    const int qt = half ? pidx : (15 - pidx);
    const int q0 = qt * 128;
    const int q0w = q0 + w*16;             // this wave's 16 q rows

    bf16x8 aq[2];
#pragma unroll
    for (int kc = 0; kc < 2; ++kc)
      aq[kc] = *(const bf16x8*)(qb + bhO + (size_t)(q0w + c)*D_ + kc*32 + g*8);

    f32x4 po[4];
    f32x4 ls;
    float mrun = -1e30f;
#pragma unroll
    for (int nd = 0; nd < 4; ++nd) po[nd] = (f32x4){0.f,0.f,0.f,0.f};
    ls = (f32x4){0.f,0.f,0.f,0.f};

    const int nkt = (q0 + 128) >> 6;       // = 2(qt+1), always >= 2

    // prologue: stage tile 0 -> buf0; drain; barrier
    gld_lds16(srcK, smem + dstP2);
    gld_lds16(srcV, smem + 8192 + dstP2);
    asm volatile("s_waitcnt vmcnt(0)" ::: "memory");
    __builtin_amdgcn_s_barrier();
    __builtin_amdgcn_sched_barrier(0);

    for (int it = 0; it < nkt; ++it) {
      const int kv0 = it * 64;
      const int cur = (it & 1) * 16384;
      const bool staging = (it + 1 < nkt);

      // stage tile it+1 into the other buffer (its readers retired at the
      // previous iteration's end-barrier)
      if (staging) {
        const int wb = 16384 - cur;
        gld_lds16(srcK + (size_t)(kv0 + 64) * 128, smem + wb + dstP2);
        gld_lds16(srcV + (size_t)(kv0 + 64) * 2,   smem + wb + 8192 + dstP2);
      }

      if (kv0 < q0w + 16) {
        f32x4 st[4];
#pragma unroll
        for (int ni = 0; ni < 4; ++ni) st[ni] = (f32x4){0.f,0.f,0.f,0.f};
        __builtin_amdgcn_s_setprio(1);
#pragma unroll
        for (int kk = 0; kk < 2; ++kk) {
          bf16x8 bk[4];
#pragma unroll
          for (int ni = 0; ni < 4; ++ni) {
            int kn = ni*16 + c;
            int Lb = kn*128 + (kk*32 + g*8)*2;
            bk[ni] = *(const bf16x8*)(smem + cur + (Lb ^ ((kn & 7) << 4)));
          }
#pragma unroll
          for (int ni = 0; ni < 4; ++ni)
            st[ni] = __builtin_amdgcn_mfma_f32_16x16x32_bf16(bk[ni], aq[kk], st[ni], 0, 0, 0);
        }
        __builtin_amdgcn_s_setprio(0);

        if (kv0 + 64 > q0w) {
          const int qq = q0w + c;
#pragma unroll
          for (int ni = 0; ni < 4; ++ni)
#pragma unroll
            for (int r = 0; r < 4; ++r) {
              int kvv = kv0 + ni*16 + g*4 + r;
              if (kvv > qq) st[ni][r] = -1e30f;
            }
        }

        {
          float mn[4];
#pragma unroll
          for (int ni = 0; ni < 4; ++ni)
            mn[ni] = fmaxf(fmaxf(st[ni][0], st[ni][1]), fmaxf(st[ni][2], st[ni][3]));
          float mt = fmaxf(fmaxf(mn[0], mn[1]), fmaxf(mn[2], mn[3]));
          mt = fmaxf(mt, __shfl_xor(mt, 16));
          mt = fmaxf(mt, __shfl_xor(mt, 32));
          float m_use = mrun;
          if (__any(mt > m_use + 8.f)) {
            float mnew = fmaxf(m_use, mt);
            float alpha = exp2_fast(m_use - mnew);
            mrun = mnew;
            m_use = mnew;
#pragma unroll
            for (int r = 0; r < 4; ++r) ls[r] *= alpha;
#pragma unroll
            for (int nd = 0; nd < 4; ++nd)
#pragma unroll
              for (int r = 0; r < 4; ++r) po[nd][r] *= alpha;
          }
#pragma unroll
          for (int ni = 0; ni < 4; ++ni)
#pragma unroll
            for (int r = 0; r < 4; ++r)
              st[ni][r] = exp2_fast(st[ni][r] - m_use);
        }

        {
          const int row = c;
          const int sw = (row & 7) << 4;
          const int rb = pbase + row*128;
#pragma unroll
          for (int ni = 0; ni < 4; ++ni) {
            unsigned u0, u1;
            asm("v_cvt_pk_bf16_f32 %0, %1, %2" : "=v"(u0) : "v"(st[ni][0]), "v"(st[ni][1]));
            asm("v_cvt_pk_bf16_f32 %0, %1, %2" : "=v"(u1) : "v"(st[ni][2]), "v"(st[ni][3]));
            int Lb = (ni*16 + g*4) * 2;
            uint2 uu; uu.x = u0; uu.y = u1;
            *(uint2*)(smem + rb + (Lb ^ sw)) = uu;
          }
        }

        __builtin_amdgcn_s_setprio(1);
#pragma unroll
        for (int kk = 0; kk < 2; ++kk) {
          bf16x8 pb;
          {
            int pr = c;
            int Lb = pr*128 + (kk*32 + g*8)*2;
            pb = *(const bf16x8*)(smem + pbase + (Lb ^ ((pr & 7) << 4)));
          }
          ls = __builtin_amdgcn_mfma_f32_16x16x32_bf16(vones, pb, ls, 0, 0, 0);
          bf16x8 bv[4];
#pragma unroll
          for (int nd = 0; nd < 4; ++nd) {
            int vr = nd*16 + c;
            int Lb = vr*128 + (kk*32 + g*8)*2;
            bv[nd] = *(const bf16x8*)(smem + cur + 8192 + (Lb ^ ((vr & 7) << 4)));
          }
#pragma unroll
          for (int nd = 0; nd < 4; ++nd)
            po[nd] = __builtin_amdgcn_mfma_f32_16x16x32_bf16(bv[nd], pb, po[nd], 0, 0, 0);
        }
        __builtin_amdgcn_s_setprio(0);
      }

      // gate: drain this iter's stage (issued a full compute phase ago);
      // barrier protects both KV buffers and the P region
      if (staging) { asm volatile("s_waitcnt vmcnt(0)" ::: "memory"); }
      __builtin_amdgcn_s_barrier();
      __builtin_amdgcn_sched_barrier(0);
    }

    {
      float inv = 1.f / ls[0];
      int t = q0w + c;
#pragma unroll
      for (int nd = 0; nd < 4; ++nd) {
        ushort4 o;
        o.x = f2bf(po[nd][0] * inv);
        o.y = f2bf(po[nd][1] * inv);
        o.z = f2bf(po[nd][2] * inv);
        o.w = f2bf(po[nd][3] * inv);
        *(ushort4*)(yb + ((size_t)b*T_ + t)*C_ + h*64 + nd*16 + g*4) = o;
      }
    }
  }
}

// ---------------------------------------------------------------- launcher
extern "C" void kernel_launch(void* const* d_in, const int* in_sizes, int n_in,
                              void* d_out, int out_size, void* d_ws, size_t ws_size,
                              hipStream_t stream)
{
  const float* x  = (const float*)d_in[0];
  const float* Wq = (const float*)d_in[1];
  const float* Wk = (const float*)d_in[2];
  const float* Wv = (const float*)d_in[3];
  const float* Wp = (const float*)d_in[4];
  const int*   sp = (const int*)d_in[5];
  float* out = (float*)d_out;

  char* ws = (char*)d_ws;
  unsigned short* xb   = (unsigned short*)(ws);                  // 16 MB
  unsigned short* wcat = (unsigned short*)(ws + 16777216);       // 6 MB [Wq;Wk;Wv]
  unsigned short* wpb  = (unsigned short*)(ws + 23068672);       // 2 MB
  unsigned short* qb   = (unsigned short*)(ws + 25165824);       // 16 MB (B,H,T,D)
  unsigned short* kb   = (unsigned short*)(ws + 41943040);       // 16 MB (B,H,T,D)
  unsigned short* vt   = (unsigned short*)(ws + 58720256);       // 16 MB (B,H,D,T)
  unsigned short* yb   = (unsigned short*)(ws + 75497472);       // 16 MB (B*T, C)
  float* cosT = (float*)(ws + 92274688);                         // 512 KB [T][D]
  float* sinT = (float*)(ws + 92798976);                         // 512 KB [T][D]

  k_convert<<<dim3(2048), dim3(256), 0, stream>>>(x, Wq, Wk, Wv, Wp, xb, wcat, wpb);
  k_rope_tab<<<dim3(512), dim3(256), 0, stream>>>(sp, cosT, sinT);
  k_gemm256<<<dim3(32, 16), dim3(1024), 0, stream>>>(xb, wcat, qb, kb, vt, cosT, sinT);
  k_attn<<<dim3(64, 8), dim3(512), 0, stream>>>(qb, kb, vt, yb);
  k_gemm1<<<dim3(64, 8), dim3(512), 0, stream>>>(yb, wpb, out);
}